// Round 1
// 131.030 us; speedup vs baseline: 1.0422x; 1.0422x over previous
//
#include <hip/hip_runtime.h>

#define NB 32
#define NP 4096
#define NM 12
#define NW 9
#define NC 64          // IN_C == OUT_C == 64
#define PN_PAD 4097
#define KDIM (NW * NC)     // 576
#define NKS (KDIM / 16)    // 36 K-steps of the 32x32x16 MFMA
#define AROW 584           // 576 + 8 pad shorts (16B-aligned rows)

#define WSW_BYTES (KDIM * NC * 2)            // 73728 B  bf16 swizzled weights
#define W2_OFFSET WSW_BYTES
#define W2_BYTES (NP * NM * 12 * 4)          // 2359296 B  w2d
#define XB_OFFSET (W2_OFFSET + W2_BYTES)     // 2433024
#define XB_BYTES (NB * PN_PAD * NC * 2)      // 16781312 B  bf16 x
#define WS_NEED ((size_t)XB_OFFSET + XB_BYTES)

typedef __attribute__((ext_vector_type(8))) short short8;
typedef __attribute__((ext_vector_type(2))) float float2v;
typedef __attribute__((ext_vector_type(4))) float float4v;
typedef __attribute__((ext_vector_type(16))) float float16v;

__device__ __forceinline__ unsigned short f32_to_bf16(float f) {
    union { float f; unsigned u; } v; v.f = f;
    unsigned r = v.u + 0x7FFFu + ((v.u >> 16) & 1u);  // RNE
    return (unsigned short)(r >> 16);
}

// Pack float4 -> 4 bf16 (round via +0x8000, take high 16 bits)
__device__ __forceinline__ uint2 pack_bf16x4(float4v v) {
    union { float f; unsigned u; } a0, a1, a2, a3;
    a0.f = v[0]; a1.f = v[1]; a2.f = v[2]; a3.f = v[3];
    unsigned u0 = a0.u + 0x8000u, u1 = a1.u + 0x8000u;
    unsigned u2 = a2.u + 0x8000u, u3 = a3.u + 0x8000u;
    uint2 r;
    r.x = __builtin_amdgcn_perm(u1, u0, 0x07060302u);
    r.y = __builtin_amdgcn_perm(u3, u2, 0x07060302u);
    return r;
}

// Pack two float2 (lo = ch0,1 / hi = ch2,3) -> 4 bf16
__device__ __forceinline__ uint2 pack_bf16x4_2(float2v lo, float2v hi) {
    union { float f; unsigned u; } a0, a1, a2, a3;
    a0.f = lo[0]; a1.f = lo[1]; a2.f = hi[0]; a3.f = hi[1];
    unsigned u0 = a0.u + 0x8000u, u1 = a1.u + 0x8000u;
    unsigned u2 = a2.u + 0x8000u, u3 = a3.u + 0x8000u;
    uint2 r;
    r.x = __builtin_amdgcn_perm(u1, u0, 0x07060302u);
    r.y = __builtin_amdgcn_perm(u3, u2, 0x07060302u);
    return r;
}

// 4 packed bf16 -> two float2 (bf16->f32 is a 16-bit left shift)
__device__ __forceinline__ void bf16x4_to_2xf2(uint2 u, float2v& lo, float2v& hi) {
    union { unsigned u; float f; } c0, c1, c2, c3;
    c0.u = u.x << 16; c1.u = u.x & 0xFFFF0000u;
    c2.u = u.y << 16; c3.u = u.y & 0xFFFF0000u;
    lo = (float2v){c0.f, c1.f};
    hi = (float2v){c2.f, c3.f};
}

// Fused prep:
//  (a) swizzle weights fp32 -> bf16 in 32x32x16 MFMA B-fragment order
//      frag f = ks*2 + nt2; lane holds col = nt2*32 + (lane&31),
//      k = ks*16 + (lane>>5)*8 + j
//  (b) w2d[(p*12+m)*12 + w] = ww[p,m,w] * mask[p,m]
//  (c) (DOX) x fp32 -> bf16 rows
template<int DOX>
__global__ void prep_all(const float* __restrict__ w,
                         const float* __restrict__ ww,
                         const float* __restrict__ mask,
                         const float* __restrict__ x,
                         unsigned short* __restrict__ wsw,
                         float* __restrict__ w2d,
                         unsigned short* __restrict__ xb) {
    int idx = blockIdx.x * 256 + threadIdx.x;
    if (idx < KDIM * NC) {
        int j    = idx & 7;
        int lane = (idx >> 3) & 63;
        int f    = idx >> 9;       // 0..71  = ks*2 + nt2
        int nt2  = f & 1;
        int ks   = f >> 1;         // 0..35
        int k = ks * 16 + ((lane >> 5) * 8) + j;   // k = w*64 + i
        int n = nt2 * 32 + (lane & 31);            // n = o
        int wi = k >> 6;
        int ii = k & 63;
        wsw[idx] = f32_to_bf16(w[wi * (NC * NC) + n * NC + ii]);
    }
    if (idx < NP * NM * NW) {
        int wq = idx % NW;
        int pm = idx / NW;       // p*12 + m
        w2d[pm * 12 + wq] = ww[idx] * mask[pm];
    }
    if (DOX) {
        const int n4 = NB * PN_PAD * NC / 4;  // 2097664
        if (idx < n4) {
            const float4v* x4 = (const float4v*)x;
            ((uint2*)xb)[idx] = pack_bf16x4(x4[idx]);
        }
    }
}

// One block (512 threads) per p.
// Phase 1: t[b, w*64+i] (32 x 576) fp32 acc (packed-f32 FMA) -> bf16 LDS tile.
// Phase 2: 2 waves only, each one 32x32x16-MFMA N-tile over K=576 (wsw read 1x/block).
template<int BF16X>
__global__ __launch_bounds__(512)
void conv_main(const float* __restrict__ x,            // used only when !BF16X
               const unsigned short* __restrict__ xb,  // (32, 4097, 64) bf16
               const unsigned short* __restrict__ wsw,
               const float* __restrict__ bias,
               const float* __restrict__ w2d,
               const int* __restrict__ nid,
               float* __restrict__ out) {
    __shared__ __align__(16) unsigned short A[NB * AROW];

    const int p = blockIdx.x;
    const int tid = threadIdx.x;

    // ---- Phase 1 ----
    {
        const int i4 = tid & 15;   // 4-channel group within the 64-ch row
        const int b  = tid >> 4;   // 0..31
        const float* w2p = w2d + p * (NM * 12);
        const int* nidp = nid + p * NM;

        int nm[NM];
        #pragma unroll
        for (int m = 0; m < NM; ++m) nm[m] = nidp[m];  // uniform -> SGPRs

        float2v acc0[NW], acc1[NW];
        #pragma unroll
        for (int w = 0; w < NW; ++w) {
            acc0[w] = (float2v){0.f, 0.f};
            acc1[w] = (float2v){0.f, 0.f};
        }

        if (BF16X) {
            const uint2* xb2 = (const uint2*)xb;   // row = 16 uint2 (128 B)
            uint2 xv[NM];
            #pragma unroll
            for (int m = 0; m < NM; ++m)
                xv[m] = xb2[(b * PN_PAD + nm[m]) * 16 + i4];
            #pragma unroll
            for (int m = 0; m < NM; ++m) {
                float2v lo, hi;
                bf16x4_to_2xf2(xv[m], lo, hi);
                #pragma unroll
                for (int w = 0; w < NW; ++w) {
                    const float ws = w2p[m * 12 + w];
                    acc0[w] += lo * ws;   // -> v_pk_fma_f32
                    acc1[w] += hi * ws;
                }
            }
        } else {
            const float4v* x4 = (const float4v*)x;
            float4v xv[NM];
            #pragma unroll
            for (int m = 0; m < NM; ++m)
                xv[m] = x4[(b * PN_PAD + nm[m]) * 16 + i4];
            #pragma unroll
            for (int m = 0; m < NM; ++m) {
                const float2v lo = {xv[m][0], xv[m][1]};
                const float2v hi = {xv[m][2], xv[m][3]};
                #pragma unroll
                for (int w = 0; w < NW; ++w) {
                    const float ws = w2p[m * 12 + w];
                    acc0[w] += lo * ws;
                    acc1[w] += hi * ws;
                }
            }
        }

        #pragma unroll
        for (int w = 0; w < NW; ++w)
            *(uint2*)&A[b * AROW + w * 64 + i4 * 4] = pack_bf16x4_2(acc0[w], acc1[w]);
    }
    __syncthreads();

    // ---- Phase 2 : 2 waves, 32x32x16 MFMA ----
    {
        const int lane = tid & 63;
        const int wid  = tid >> 6;
        if (wid < 2) {
            const int col  = lane & 31;   // output channel within this N-tile
            const int half = lane >> 5;   // k-subgroup
            float16v acc = {0.f,0.f,0.f,0.f, 0.f,0.f,0.f,0.f,
                            0.f,0.f,0.f,0.f, 0.f,0.f,0.f,0.f};
            const short8* Bfrags = (const short8*)wsw;

            #pragma unroll
            for (int ks = 0; ks < NKS; ++ks) {
                short8 bfrag = Bfrags[(ks * 2 + wid) * 64 + lane];
                const short8 a = *(const short8*)&A[col * AROW + ks * 16 + half * 8];
                acc = __builtin_amdgcn_mfma_f32_32x32x16_bf16(a, bfrag, acc, 0, 0, 0);
            }

            const int o = wid * 32 + col;
            const float bv = bias[o];
            // C/D layout (HW-verified): col=lane&31, row=(reg&3)+8*(reg>>2)+4*(lane>>5)
            #pragma unroll
            for (int reg = 0; reg < 16; ++reg) {
                const int b = (reg & 3) + 8 * (reg >> 2) + 4 * half;
                out[(b * NP + p) * NC + o] = acc[reg] + bv;
            }
        }
    }
}

extern "C" void kernel_launch(void* const* d_in, const int* in_sizes, int n_in,
                              void* d_out, int out_size, void* d_ws, size_t ws_size,
                              hipStream_t stream) {
    const float* x    = (const float*)d_in[0];
    const float* w    = (const float*)d_in[1];
    const float* bias = (const float*)d_in[2];
    const float* ww   = (const float*)d_in[3];
    const int*   nid  = (const int*)d_in[4];
    const float* mask = (const float*)d_in[5];
    float* out = (float*)d_out;
    unsigned short* wsw = (unsigned short*)d_ws;
    float* w2d = (float*)((char*)d_ws + W2_OFFSET);
    unsigned short* xb = (unsigned short*)((char*)d_ws + XB_OFFSET);

    if (ws_size >= WS_NEED) {
        const int n4 = NB * PN_PAD * NC / 4;  // 2097664 — sizes the fused prep grid
        hipLaunchKernelGGL(prep_all<1>, dim3((n4 + 255) / 256), dim3(256), 0, stream,
                           w, ww, mask, x, wsw, w2d, xb);
        hipLaunchKernelGGL(conv_main<1>, dim3(NP), dim3(512), 0, stream,
                           x, xb, wsw, bias, w2d, nid, out);
    } else {
        const int prep_elems = NP * NM * NW;  // 442368 covers wsw + w2d jobs
        hipLaunchKernelGGL(prep_all<0>, dim3((prep_elems + 255) / 256), dim3(256), 0, stream,
                           w, ww, mask, x, wsw, w2d, xb);
        hipLaunchKernelGGL(conv_main<0>, dim3(NP), dim3(512), 0, stream,
                           x, xb, wsw, bias, w2d, nid, out);
    }
}